// Round 4
// baseline (7667.567 us; speedup 1.0000x reference)
//
#include <hip/hip_runtime.h>
#include <hip/hip_bf16.h>

// MLA prefill: B=1, T=2048, C=2048, H=16, DN=128, DR=64, DV=128, QKD=192,
// RQ=1536, RKV=512.
// Round 4: inputs float32 AND output float32 (reference output dtype is
// jnp.float32; the test label's "bf16" is a hard-coded string). Round-3's
// err=1.99 signature matched bf16-written-into-f32-buffer exactly.

#define T_DIM 2048
#define C_DIM 2048
#define H_DIM 16
#define SCALE_F 0.07216878364870322f   // 192^-0.5
#define EPS_F 1e-6f
#define NEG_INF (-3.402823466e38f)

// C[M,N] = A[M,K] @ W[N,K]^T + bias[N].  A row stride = lda.
// All dims are multiples of 16 in this problem; no bounds checks.
__global__ void gemm_nt_kernel(const float* __restrict__ A, int lda,
                               const float* __restrict__ W,
                               const float* __restrict__ bias,
                               float* __restrict__ C,
                               int M, int N, int K) {
    __shared__ float As[16][17];
    __shared__ float Ws[16][17];
    const int tx = threadIdx.x, ty = threadIdx.y;
    const int row = blockIdx.y * 16 + ty;
    const int col = blockIdx.x * 16 + tx;
    float acc = 0.f;
    for (int k0 = 0; k0 < K; k0 += 16) {
        As[ty][tx] = A[(size_t)row * lda + k0 + tx];
        Ws[ty][tx] = W[(size_t)(blockIdx.x * 16 + ty) * K + k0 + tx];
        __syncthreads();
#pragma unroll
        for (int kk = 0; kk < 16; kk++)
            acc += As[ty][kk] * Ws[tx][kk];
        __syncthreads();
    }
    C[(size_t)row * N + col] = acc + bias[col];
}

// In-place RMSNorm over last dim D (row stride `stride`).
__global__ void rmsnorm_kernel(float* __restrict__ buf,
                               const float* __restrict__ w,
                               int D, int stride) {
    const int row = blockIdx.x;
    float* p = buf + (size_t)row * stride;
    const int tid = threadIdx.x;  // 256 threads
    float ss = 0.f;
    for (int i = tid; i < D; i += 256) {
        float v = p[i];
        ss += v * v;
    }
    __shared__ float red[256];
    red[tid] = ss;
    __syncthreads();
    for (int off = 128; off > 0; off >>= 1) {
        if (tid < off) red[tid] += red[tid + off];
        __syncthreads();
    }
    const float scale = rsqrtf(red[0] / (float)D + EPS_F);
    for (int i = tid; i < D; i += 256)
        p[i] = p[i] * scale * w[i];
}

// RoPE on q_pe: q is (T, H*192) f32; rotate dims [128,192) per (t,h).
// grid = T blocks, block = 512 threads (h = tid>>5, pair i = tid&31).
__global__ void rope_q_kernel(float* __restrict__ q,
                              const float* __restrict__ freqs) {
    const int t = blockIdx.x;
    const int tid = threadIdx.x;
    const int h = tid >> 5;
    const int i = tid & 31;
    const float f = freqs[t * 32 + i];
    const float c = cosf(f), s = sinf(f);
    const size_t base = (size_t)t * (H_DIM * 192) + h * 192 + 128 + 2 * i;
    const float xr = q[base], xi = q[base + 1];
    q[base]     = xr * c - xi * s;
    q[base + 1] = xr * s + xi * c;
}

// RoPE on k_pe: read kvpe (T,576) cols [512,576), write kpe (T,64).
// total threads = T*32 = 65536; grid 256 x block 256.
__global__ void rope_k_kernel(const float* __restrict__ kvpe,
                              const float* __restrict__ freqs,
                              float* __restrict__ kpe) {
    const int idx = blockIdx.x * 256 + threadIdx.x;
    const int t = idx >> 5;
    const int i = idx & 31;
    const float f = freqs[t * 32 + i];
    const float c = cosf(f), s = sinf(f);
    const float* src = kvpe + (size_t)t * 576 + 512 + 2 * i;
    const float xr = src[0], xi = src[1];
    kpe[(size_t)t * 64 + 2 * i]     = xr * c - xi * s;
    kpe[(size_t)t * 64 + 2 * i + 1] = xr * s + xi * c;
}

// Flash-style causal attention, one block per (t, h), 128 threads.
// q:   (T, H*192) f32 (pe part already roped)
// kvb: (T, H*256) f32; per h: [0,128) = k_nope, [128,256) = v
// kpe: (T, 64) f32 (shared across heads)
// y:   (T, H*128) f32
__global__ void attn_kernel(const float* __restrict__ q,
                            const float* __restrict__ kvb,
                            const float* __restrict__ kpe,
                            float* __restrict__ y) {
    const int t = blockIdx.x;
    const int h = blockIdx.y;
    const int tid = threadIdx.x;  // 0..127

    __shared__ float qs[192];
    __shared__ float sc[128];
    __shared__ float red[128];

    for (int i = tid; i < 192; i += 128)
        qs[i] = q[(size_t)t * (H_DIM * 192) + h * 192 + i];
    __syncthreads();  // qs fully written before any lane reads it

    float acc = 0.f;  // output dim d == tid
    float m = NEG_INF, l = 0.f;

    for (int s0 = 0; s0 <= t; s0 += 128) {
        const int s = s0 + tid;
        float score = NEG_INF;
        if (s <= t) {
            const float* kn = kvb + (size_t)s * (H_DIM * 256) + h * 256;
            const float* kp = kpe + (size_t)s * 64;
            float d0 = 0.f;
#pragma unroll 8
            for (int i = 0; i < 128; i++) d0 += qs[i] * kn[i];
#pragma unroll 8
            for (int i = 0; i < 64; i++) d0 += qs[128 + i] * kp[i];
            score = d0 * SCALE_F;
        }
        __syncthreads();  // prior-iter reads of sc/red done before overwrite
        red[tid] = score;
        __syncthreads();
        for (int off = 64; off > 0; off >>= 1) {
            if (tid < off) red[tid] = fmaxf(red[tid], red[tid + off]);
            __syncthreads();
        }
        const float m_new = fmaxf(m, red[0]);
        __syncthreads();  // everyone read red[0] before reuse
        const float p = (s <= t) ? __expf(score - m_new) : 0.f;
        red[tid] = p;
        sc[tid] = p;
        __syncthreads();
        for (int off = 64; off > 0; off >>= 1) {
            if (tid < off) red[tid] += red[tid + off];
            __syncthreads();
        }
        const float psum = red[0];
        const float alpha = __expf(m - m_new);  // 0 when m==-inf
        l = l * alpha + psum;
        m = m_new;

        int lim = t - s0 + 1;
        if (lim > 128) lim = 128;
        acc *= alpha;
        const float* vbase = kvb + (size_t)s0 * (H_DIM * 256) + h * 256 + 128 + tid;
        for (int j = 0; j < lim; j++)
            acc += sc[j] * vbase[(size_t)j * (H_DIM * 256)];
    }

    y[(size_t)t * (H_DIM * 128) + h * 128 + tid] = acc / l;
}

extern "C" void kernel_launch(void* const* d_in, const int* in_sizes, int n_in,
                              void* d_out, int out_size, void* d_ws, size_t ws_size,
                              hipStream_t stream) {
    const float* x         = (const float*)d_in[0];
    const float* freqs     = (const float*)d_in[1];
    const float* wq_a      = (const float*)d_in[2];
    const float* bq_a      = (const float*)d_in[3];
    const float* q_norm_w  = (const float*)d_in[4];
    const float* wq_b      = (const float*)d_in[5];
    const float* bq_b      = (const float*)d_in[6];
    const float* wkv_a     = (const float*)d_in[7];
    const float* bkv_a     = (const float*)d_in[8];
    const float* kv_norm_w = (const float*)d_in[9];
    const float* wkv_b     = (const float*)d_in[10];
    const float* bkv_b     = (const float*)d_in[11];
    const float* wo        = (const float*)d_in[12];
    const float* bo        = (const float*)d_in[13];
    float* out = (float*)d_out;   // reference output dtype is float32

    // Packed workspace (f32 elements), total 19,136,512 floats = 76.5 MB:
    //   [q_lat 2048x1536][kvpe 2048x576][qb 2048x3072][kvb 2048x4096][kpe 2048x64]
    //   yb (2048x2048) aliases the q_lat+kvpe region (both dead before attn).
    float* base  = (float*)d_ws;
    float* q_lat = base;                               // 3,145,728
    float* kvpe  = q_lat + (size_t)2048 * 1536;        // 1,179,648
    float* qb    = kvpe  + (size_t)2048 * 576;         // 6,291,456
    float* kvb   = qb    + (size_t)2048 * 3072;        // 8,388,608
    float* kpe   = kvb   + (size_t)2048 * 4096;        // 131,072
    float* yb    = base;                               // aliases q_lat+kvpe (4,325,376 >= 4,194,304)

    dim3 blk(16, 16);

    // q_lat = x @ wq_a^T + bq_a
    gemm_nt_kernel<<<dim3(1536 / 16, 2048 / 16), blk, 0, stream>>>(x, 2048, wq_a, bq_a, q_lat, 2048, 1536, 2048);
    // rmsnorm(q_lat)
    rmsnorm_kernel<<<2048, 256, 0, stream>>>(q_lat, q_norm_w, 1536, 1536);
    // q = q_lat @ wq_b^T + bq_b
    gemm_nt_kernel<<<dim3(3072 / 16, 2048 / 16), blk, 0, stream>>>(q_lat, 1536, wq_b, bq_b, qb, 2048, 3072, 1536);
    // kvpe = x @ wkv_a^T + bkv_a
    gemm_nt_kernel<<<dim3(576 / 16, 2048 / 16), blk, 0, stream>>>(x, 2048, wkv_a, bkv_a, kvpe, 2048, 576, 2048);
    // rope q_pe (in place on qb)
    rope_q_kernel<<<2048, 512, 0, stream>>>(qb, freqs);
    // rope k_pe -> kpe
    rope_k_kernel<<<256, 256, 0, stream>>>(kvpe, freqs, kpe);
    // rmsnorm(kv_lat) in place on kvpe cols [0,512)
    rmsnorm_kernel<<<2048, 256, 0, stream>>>(kvpe, kv_norm_w, 512, 576);
    // kvb = kv_lat_n @ wkv_b^T + bkv_b   (A stride 576)
    gemm_nt_kernel<<<dim3(4096 / 16, 2048 / 16), blk, 0, stream>>>(kvpe, 576, wkv_b, bkv_b, kvb, 2048, 4096, 512);
    // attention -> yb (aliases dead q_lat/kvpe arenas)
    attn_kernel<<<dim3(2048, 16), 128, 0, stream>>>(qb, kvb, kpe, yb);
    // out = yb @ wo^T + bo  (f32 store)
    gemm_nt_kernel<<<dim3(2048 / 16, 2048 / 16), blk, 0, stream>>>(yb, 2048, wo, bo, out, 2048, 2048, 2048);
}

// Round 5
// 4013.044 us; speedup vs baseline: 1.9107x; 1.9107x over previous
//
#include <hip/hip_runtime.h>
#include <hip/hip_bf16.h>

// MLA prefill: B=1, T=2048, C=2048, H=16, DN=128, DR=64, DV=128, QKD=192,
// RQ=1536, RKV=512. Inputs f32, output f32.
// Round 5: MFMA flash attention (bf16 QKV, f32 online softmax in registers).
// GEMMs remain scalar f32 (next round: MFMA GEMM).

#define T_DIM 2048
#define H_DIM 16
#define SCALE_F 0.07216878364870322f   // 192^-0.5
#define EPS_F 1e-6f
#define NEG_INF (-3.402823466e38f)

typedef __attribute__((ext_vector_type(8))) short short8;
typedef __attribute__((ext_vector_type(4))) float f32x4;

__device__ inline float to_f(float v) { return v; }
__device__ inline float to_f(__hip_bfloat16 v) { return __bfloat162float(v); }
__device__ inline void st_out(float* p, float v) { *p = v; }
__device__ inline void st_out(__hip_bfloat16* p, float v) { *p = __float2bfloat16(v); }

// ---------------- scalar GEMM (unchanged structure, templated dtypes) -------
// C[M,N] = A[M,K] @ W[N,K]^T + bias[N].  A row stride lda. Dims % 16 == 0
// except N=576 case also %16==0. W,bias are f32.
template <typename AT, typename OT>
__global__ void gemm_nt_kernel(const AT* __restrict__ A, int lda,
                               const float* __restrict__ W,
                               const float* __restrict__ bias,
                               OT* __restrict__ C,
                               int M, int N, int K) {
    __shared__ float As[16][17];
    __shared__ float Ws[16][17];
    const int tx = threadIdx.x, ty = threadIdx.y;
    const int row = blockIdx.y * 16 + ty;
    const int col = blockIdx.x * 16 + tx;
    float acc = 0.f;
    for (int k0 = 0; k0 < K; k0 += 16) {
        As[ty][tx] = to_f(A[(size_t)row * lda + k0 + tx]);
        Ws[ty][tx] = W[(size_t)(blockIdx.x * 16 + ty) * K + k0 + tx];
        __syncthreads();
#pragma unroll
        for (int kk = 0; kk < 16; kk++)
            acc += As[ty][kk] * Ws[tx][kk];
        __syncthreads();
    }
    st_out(&C[(size_t)row * N + col], acc + bias[col]);
}

// ---------------- RMSNorm: f32 in -> OT out (separate buffers/strides) ------
template <typename OT>
__global__ void rmsnorm_kernel(const float* __restrict__ in, OT* __restrict__ outp,
                               const float* __restrict__ w,
                               int D, int in_stride, int out_stride) {
    const int row = blockIdx.x;
    const float* p = in + (size_t)row * in_stride;
    OT* o = outp + (size_t)row * out_stride;
    const int tid = threadIdx.x;  // 256
    float ss = 0.f;
    for (int i = tid; i < D; i += 256) { float v = p[i]; ss += v * v; }
    __shared__ float red[256];
    red[tid] = ss;
    __syncthreads();
    for (int off = 128; off > 0; off >>= 1) {
        if (tid < off) red[tid] += red[tid + off];
        __syncthreads();
    }
    const float scale = rsqrtf(red[0] / (float)D + EPS_F);
    for (int i = tid; i < D; i += 256)
        st_out(&o[i], p[i] * scale * w[i]);
}

// ---------------- RoPE on q (in-place on bf16 qb: (T, H*192)) ---------------
// 1,048,576 threads: t=idx>>9, h=(idx>>5)&15, i=idx&31; rotate dims 128+2i.
__global__ void rope_q_bf_kernel(__hip_bfloat16* __restrict__ qb,
                                 const float* __restrict__ freqs) {
    const int idx = blockIdx.x * 256 + threadIdx.x;
    const int t = idx >> 9;
    const int h = (idx >> 5) & 15;
    const int i = idx & 31;
    const float f = freqs[t * 32 + i];
    const float c = cosf(f), s = sinf(f);
    __hip_bfloat16* p = qb + (size_t)t * 3072 + h * 192 + 128 + 2 * i;
    const float xr = __bfloat162float(p[0]), xi = __bfloat162float(p[1]);
    p[0] = __float2bfloat16(xr * c - xi * s);
    p[1] = __float2bfloat16(xr * s + xi * c);
}

// ---------------- RoPE on k_pe: kvpe f32 (T,576) cols[512:576) -> kpe bf16 --
__global__ void rope_k_bf_kernel(const float* __restrict__ kvpe,
                                 const float* __restrict__ freqs,
                                 __hip_bfloat16* __restrict__ kpe) {
    const int idx = blockIdx.x * 256 + threadIdx.x;  // 65536
    const int t = idx >> 5;
    const int i = idx & 31;
    const float f = freqs[t * 32 + i];
    const float c = cosf(f), s = sinf(f);
    const float* src = kvpe + (size_t)t * 576 + 512 + 2 * i;
    const float xr = src[0], xi = src[1];
    kpe[(size_t)t * 64 + 2 * i]     = __float2bfloat16(xr * c - xi * s);
    kpe[(size_t)t * 64 + 2 * i + 1] = __float2bfloat16(xr * s + xi * c);
}

// ---------------- pack V transposed: kvb_bf (T,H*256) -> vT (H,128,T) -------
// block = (t-tile of 64, head), 256 threads; 64x128 tile via LDS.
__global__ void pack_vT_kernel(const __hip_bfloat16* __restrict__ kvb,
                               __hip_bfloat16* __restrict__ vT) {
    const int t0 = blockIdx.x * 64;
    const int h = blockIdx.y;
    const int tid = threadIdx.x;
    __shared__ __hip_bfloat16 Ls[64][136];  // pad 128->136 (2-way banks, free)
#pragma unroll
    for (int it = 0; it < 4; ++it) {        // 1024 16B granules
        int c = tid + 256 * it;
        int i = c >> 4, part = c & 15;
        *(uint4*)&Ls[i][part * 8] =
            *(const uint4*)(kvb + (size_t)(t0 + i) * 4096 + h * 256 + 128 + part * 8);
    }
    __syncthreads();
#pragma unroll
    for (int it = 0; it < 32; ++it) {       // 8192 scalar b16, coalesced over t
        int c = tid + 256 * it;
        int d = c >> 6, i = c & 63;
        vT[((size_t)(h * 128 + d)) * 2048 + t0 + i] = Ls[i][d];
    }
}

// ---------------- MFMA flash attention --------------------------------------
// q:(T,H*192) bf16 roped; kv:(T,H*256) bf16 (per h: k_nope[0:128), v[128:256));
// kpe:(T,64) bf16; vT:(H,128,T) bf16; y:(T,H*128) f32.
// Block = 64 q-rows x 1 head, 4 waves (each 16 rows). Key tiles of 64.
__global__ __launch_bounds__(256) void attn_mfma_kernel(
    const __hip_bfloat16* __restrict__ q,
    const __hip_bfloat16* __restrict__ kv,
    const __hip_bfloat16* __restrict__ kpe,
    const __hip_bfloat16* __restrict__ vT,
    float* __restrict__ y) {
    const int qt = gridDim.x - 1 - blockIdx.x;   // longest blocks first
    const int h = blockIdx.y;
    const int q0 = qt * 64;
    const int tid = threadIdx.x;
    const int w = tid >> 6, lane = tid & 63, qd = lane >> 4, lx = lane & 15;

    __shared__ __hip_bfloat16 Ks[64][200];   // 64 keys x 192 dims (pad->200)
    __shared__ __hip_bfloat16 Vs[128][72];   // 128 dv x 64 keys (pad->72)
    __shared__ __hip_bfloat16 Ps[4][16][72]; // per-wave P: 16 rows x 64 keys

    // Q A-fragments: row m = lane&15 -> q-row q0+16w+lx; k = kc*32 + qd*8
    short8 qf[6];
    {
        const __hip_bfloat16* qrow =
            q + (size_t)(q0 + 16 * w + lx) * 3072 + h * 192 + qd * 8;
#pragma unroll
        for (int kc = 0; kc < 6; ++kc)
            qf[kc] = *(const short8*)(qrow + kc * 32);
    }

    f32x4 O[8];
#pragma unroll
    for (int i = 0; i < 8; ++i) O[i] = (f32x4)(0.f);
    float mrow[4], lrow[4];
#pragma unroll
    for (int j = 0; j < 4; ++j) { mrow[j] = NEG_INF; lrow[j] = 0.f; }

    for (int s0 = 0; s0 <= q0 + 63; s0 += 64) {
        __syncthreads();  // previous tile's Ks/Vs reads done
        // stage K-tile: nope part from kv, pe part from kpe
#pragma unroll
        for (int it = 0; it < 4; ++it) {
            int c = tid + 256 * it;
            int key = c >> 4, part = c & 15;
            *(uint4*)&Ks[key][part * 8] =
                *(const uint4*)(kv + (size_t)(s0 + key) * 4096 + h * 256 + part * 8);
        }
#pragma unroll
        for (int it = 0; it < 2; ++it) {
            int c = tid + 256 * it;
            int key = c >> 3, part = c & 7;
            *(uint4*)&Ks[key][128 + part * 8] =
                *(const uint4*)(kpe + (size_t)(s0 + key) * 64 + part * 8);
        }
        // stage V-tile from vT (dv-major, keys contiguous)
#pragma unroll
        for (int it = 0; it < 4; ++it) {
            int c = tid + 256 * it;
            int dv = c >> 3, part = c & 7;
            *(uint4*)&Vs[dv][part * 8] =
                *(const uint4*)(vT + ((size_t)(h * 128 + dv)) * 2048 + s0 + part * 8);
        }
        __syncthreads();

        // S = Q K^T : 4 n-tiles (keys) x 6 k-chunks
        f32x4 S[4];
#pragma unroll
        for (int nt = 0; nt < 4; ++nt) S[nt] = (f32x4)(0.f);
#pragma unroll
        for (int kc = 0; kc < 6; ++kc) {
            short8 a = qf[kc];
#pragma unroll
            for (int nt = 0; nt < 4; ++nt) {
                short8 b = *(const short8*)&Ks[nt * 16 + lx][kc * 32 + qd * 8];
                S[nt] = __builtin_amdgcn_mfma_f32_16x16x32_bf16(a, b, S[nt], 0, 0, 0);
            }
        }

        // scale + causal mask (C layout: col = lane&15 +16nt, row = 4qd+reg)
        float sv[4][4];
#pragma unroll
        for (int nt = 0; nt < 4; ++nt) {
            int col = s0 + nt * 16 + lx;
#pragma unroll
            for (int j = 0; j < 4; ++j) {
                int row = q0 + 16 * w + 4 * qd + j;
                float v = S[nt][j] * SCALE_F;
                sv[nt][j] = (col > row) ? NEG_INF : v;
            }
        }

        // online softmax, in-register (row lives in one 16-lane quad)
        float mn[4], al[4], rs[4];
#pragma unroll
        for (int j = 0; j < 4; ++j) {
            float rm = fmaxf(fmaxf(sv[0][j], sv[1][j]), fmaxf(sv[2][j], sv[3][j]));
#pragma unroll
            for (int msk = 1; msk < 16; msk <<= 1)
                rm = fmaxf(rm, __shfl_xor(rm, msk));
            mn[j] = fmaxf(mrow[j], rm);
            al[j] = __expf(mrow[j] - mn[j]);
            rs[j] = 0.f;
        }
#pragma unroll
        for (int nt = 0; nt < 4; ++nt)
#pragma unroll
            for (int j = 0; j < 4; ++j) {
                float p = __expf(sv[nt][j] - mn[j]);
                rs[j] += p;
                Ps[w][4 * qd + j][nt * 16 + lx] = __float2bfloat16(p);
            }
#pragma unroll
        for (int j = 0; j < 4; ++j) {
#pragma unroll
            for (int msk = 1; msk < 16; msk <<= 1)
                rs[j] += __shfl_xor(rs[j], msk);
            lrow[j] = lrow[j] * al[j] + rs[j];
            mrow[j] = mn[j];
        }
#pragma unroll
        for (int nt = 0; nt < 8; ++nt)
#pragma unroll
            for (int j = 0; j < 4; ++j) O[nt][j] *= al[j];

        // wave-private LDS round-trip: ensure P writes land before reads
        asm volatile("s_waitcnt lgkmcnt(0)" ::: "memory");

        // O += P V : P A-frags (m=lane&15, k=key), V B-frags from Vs
#pragma unroll
        for (int kc2 = 0; kc2 < 2; ++kc2) {
            short8 pa = *(const short8*)&Ps[w][lx][kc2 * 32 + qd * 8];
#pragma unroll
            for (int nt = 0; nt < 8; ++nt) {
                short8 vb = *(const short8*)&Vs[nt * 16 + lx][kc2 * 32 + qd * 8];
                O[nt] = __builtin_amdgcn_mfma_f32_16x16x32_bf16(pa, vb, O[nt], 0, 0, 0);
            }
        }
    }

    // epilogue: normalize, store f32 (coalesced over lx)
#pragma unroll
    for (int j = 0; j < 4; ++j) {
        const float inv = 1.f / lrow[j];
        const int t = q0 + 16 * w + 4 * qd + j;
        float* yr = y + (size_t)t * 2048 + h * 128 + lx;
#pragma unroll
        for (int nt = 0; nt < 8; ++nt) yr[nt * 16] = O[nt][j] * inv;
    }
}

extern "C" void kernel_launch(void* const* d_in, const int* in_sizes, int n_in,
                              void* d_out, int out_size, void* d_ws, size_t ws_size,
                              hipStream_t stream) {
    const float* x         = (const float*)d_in[0];
    const float* freqs     = (const float*)d_in[1];
    const float* wq_a      = (const float*)d_in[2];
    const float* bq_a      = (const float*)d_in[3];
    const float* q_norm_w  = (const float*)d_in[4];
    const float* wq_b      = (const float*)d_in[5];
    const float* bq_b      = (const float*)d_in[6];
    const float* wkv_a     = (const float*)d_in[7];
    const float* bkv_a     = (const float*)d_in[8];
    const float* kv_norm_w = (const float*)d_in[9];
    const float* wkv_b     = (const float*)d_in[10];
    const float* bkv_b     = (const float*)d_in[11];
    const float* wo        = (const float*)d_in[12];
    const float* bo        = (const float*)d_in[13];
    float* out = (float*)d_out;

    // Workspace (~63.7 MB); yb aliases dead q_lat+kvpe (17.3 MB >= 16.8 MB).
    char* p = (char*)d_ws;
    float* q_lat = (float*)p;               p += (size_t)2048 * 1536 * 4;
    float* kvpe  = (float*)p;               p += (size_t)2048 * 576 * 4;
    __hip_bfloat16* q_lat_bf  = (__hip_bfloat16*)p; p += (size_t)2048 * 1536 * 2;
    __hip_bfloat16* qb_bf     = (__hip_bfloat16*)p; p += (size_t)2048 * 3072 * 2;
    __hip_bfloat16* kv_lat_bf = (__hip_bfloat16*)p; p += (size_t)2048 * 512 * 2;
    __hip_bfloat16* kvb_bf    = (__hip_bfloat16*)p; p += (size_t)2048 * 4096 * 2;
    __hip_bfloat16* kpe_bf    = (__hip_bfloat16*)p; p += (size_t)2048 * 64 * 2;
    __hip_bfloat16* vT        = (__hip_bfloat16*)p; p += (size_t)16 * 128 * 2048 * 2;
    float* yb = (float*)d_ws;  // alias

    dim3 blk(16, 16);

    // q_lat = x @ wq_a^T + bq_a   (f32)
    gemm_nt_kernel<float, float>
        <<<dim3(1536 / 16, 2048 / 16), blk, 0, stream>>>(x, 2048, wq_a, bq_a, q_lat, 2048, 1536, 2048);
    // rmsnorm -> bf16
    rmsnorm_kernel<__hip_bfloat16>
        <<<2048, 256, 0, stream>>>(q_lat, q_lat_bf, q_norm_w, 1536, 1536, 1536);
    // qb_bf = q_lat_bf @ wq_b^T + bq_b   (bf16 out)
    gemm_nt_kernel<__hip_bfloat16, __hip_bfloat16>
        <<<dim3(3072 / 16, 2048 / 16), blk, 0, stream>>>(q_lat_bf, 1536, wq_b, bq_b, qb_bf, 2048, 3072, 1536);
    // rope q_pe in place (bf16)
    rope_q_bf_kernel<<<4096, 256, 0, stream>>>(qb_bf, freqs);
    // kvpe = x @ wkv_a^T + bkv_a  (f32)
    gemm_nt_kernel<float, float>
        <<<dim3(576 / 16, 2048 / 16), blk, 0, stream>>>(x, 2048, wkv_a, bkv_a, kvpe, 2048, 576, 2048);
    // rope k_pe -> kpe_bf
    rope_k_bf_kernel<<<256, 256, 0, stream>>>(kvpe, freqs, kpe_bf);
    // rmsnorm kv_lat -> bf16
    rmsnorm_kernel<__hip_bfloat16>
        <<<2048, 256, 0, stream>>>(kvpe, kv_lat_bf, kv_norm_w, 512, 576, 512);
    // kvb_bf = kv_lat_bf @ wkv_b^T + bkv_b   (bf16 out)
    gemm_nt_kernel<__hip_bfloat16, __hip_bfloat16>
        <<<dim3(4096 / 16, 2048 / 16), blk, 0, stream>>>(kv_lat_bf, 512, wkv_b, bkv_b, kvb_bf, 2048, 4096, 512);
    // pack V^T
    pack_vT_kernel<<<dim3(32, 16), 256, 0, stream>>>(kvb_bf, vT);
    // MFMA flash attention -> yb f32
    attn_mfma_kernel<<<dim3(32, 16), 256, 0, stream>>>(qb_bf, kvb_bf, kpe_bf, vT, yb);
    // out = yb @ wo^T + bo  (f32)
    gemm_nt_kernel<float, float>
        <<<dim3(2048 / 16, 2048 / 16), blk, 0, stream>>>(yb, 2048, wo, bo, out, 2048, 2048, 2048);
}

// Round 6
// 470.626 us; speedup vs baseline: 16.2923x; 8.5270x over previous
//
#include <hip/hip_runtime.h>
#include <hip/hip_bf16.h>

// MLA prefill: B=1, T=2048, C=2048, H=16, DN=128, DR=64, DV=128, QKD=192,
// RQ=1536, RKV=512. Inputs f32, output f32.
// Round 6: all GEMMs -> bf16 MFMA (m97 structure: 128x128 tile, BK=32,
// global_load_lds width-16 staging). Weights cast f32->bf16 per call via a
// cycled arena; wkv_a padded to N=640 so all GEMMs are tile-exact.

#define T_DIM 2048
#define H_DIM 16
#define SCALE_F 0.07216878364870322f   // 192^-0.5
#define EPS_F 1e-6f
#define NEG_INF (-3.402823466e38f)

typedef __attribute__((ext_vector_type(8))) short short8;
typedef __attribute__((ext_vector_type(4))) float f32x4;
typedef __attribute__((address_space(3))) char lds_char;
typedef const __attribute__((address_space(1))) char glb_char;

__device__ inline void st_out(float* p, float v) { *p = v; }
__device__ inline void st_out(__hip_bfloat16* p, float v) { *p = __float2bfloat16(v); }

// ---------------- f32 -> bf16 cast (optionally zero-padded tail) ------------
// Operates on float4 granules; n4_dst >= n4_src, tail zero-filled.
__global__ void cast_bf16_kernel(const float* __restrict__ src,
                                 __hip_bfloat16* __restrict__ dst,
                                 int n4_src, int n4_dst) {
    int i = blockIdx.x * 256 + threadIdx.x;
    if (i >= n4_dst) return;
    float4 v = make_float4(0.f, 0.f, 0.f, 0.f);
    if (i < n4_src) v = ((const float4*)src)[i];
    dst[4 * i + 0] = __float2bfloat16(v.x);
    dst[4 * i + 1] = __float2bfloat16(v.y);
    dst[4 * i + 2] = __float2bfloat16(v.z);
    dst[4 * i + 3] = __float2bfloat16(v.w);
}

__global__ void pad_bias_kernel(const float* __restrict__ src, float* __restrict__ dst,
                                int n_src, int n_dst) {
    int i = blockIdx.x * 256 + threadIdx.x;
    if (i < n_dst) dst[i] = (i < n_src) ? src[i] : 0.f;
}

// ---------------- MFMA GEMM: C[M,N] = A[M,K] @ W[N,K]^T + bias[N] -----------
// A,W bf16; bias f32; OT out. M%128==0 (grid.y), N%128==0 (grid.x), K%32==0.
// 256 threads = 4 waves; wave owns a 64x64 quadrant (4x4 MFMA 16x16x32 tiles).
// LDS tiles stored lane-ordered ([128][32] row-major, 16B granule g=row*4+q)
// to satisfy global_load_lds's wave-uniform-base + lane*16 destination rule.
template <typename OT>
__global__ __launch_bounds__(256) void gemm_mfma_kernel(
    const __hip_bfloat16* __restrict__ A, int lda,
    const __hip_bfloat16* __restrict__ W, int ldw,
    const float* __restrict__ bias,
    OT* __restrict__ C, int ldc, int K) {
    __shared__ __hip_bfloat16 As[128 * 32];
    __shared__ __hip_bfloat16 Bs[128 * 32];
    const int tid = threadIdx.x;
    const int w = tid >> 6, lane = tid & 63, qd = lane >> 4, lx = lane & 15;
    const int rowB = blockIdx.y * 128, colB = blockIdx.x * 128;
    const int wr = (w >> 1) * 64, wc = (w & 1) * 64;

    f32x4 acc[4][4];
#pragma unroll
    for (int i = 0; i < 4; ++i)
#pragma unroll
        for (int j = 0; j < 4; ++j) acc[i][j] = (f32x4)(0.f);

    for (int k0 = 0; k0 < K; k0 += 32) {
        // stage 128x32 A and W tiles, 16 B/lane, 2 issues each per lane
#pragma unroll
        for (int it = 0; it < 2; ++it) {
            const int g = w * 128 + it * 64 + lane;   // 16B granule index
            const int row = g >> 2, q = g & 3;
            const __hip_bfloat16* ga = A + (size_t)(rowB + row) * lda + k0 + q * 8;
            __builtin_amdgcn_global_load_lds((glb_char*)ga,
                                             (lds_char*)((char*)As + (size_t)g * 16), 16, 0, 0);
            const __hip_bfloat16* gb = W + (size_t)(colB + row) * ldw + k0 + q * 8;
            __builtin_amdgcn_global_load_lds((glb_char*)gb,
                                             (lds_char*)((char*)Bs + (size_t)g * 16), 16, 0, 0);
        }
        __syncthreads();   // drains vmcnt (global_load_lds) before use

        short8 a[4], b[4];
#pragma unroll
        for (int rt = 0; rt < 4; ++rt)
            a[rt] = *(const short8*)&As[(wr + rt * 16 + lx) * 32 + qd * 8];
#pragma unroll
        for (int ct = 0; ct < 4; ++ct)
            b[ct] = *(const short8*)&Bs[(wc + ct * 16 + lx) * 32 + qd * 8];
#pragma unroll
        for (int rt = 0; rt < 4; ++rt)
#pragma unroll
            for (int ct = 0; ct < 4; ++ct)
                acc[rt][ct] = __builtin_amdgcn_mfma_f32_16x16x32_bf16(a[rt], b[ct], acc[rt][ct], 0, 0, 0);
        __syncthreads();   // LDS reads done before next stage overwrites
    }

    // epilogue: C/D layout col=lane&15, row=4*qd+reg
#pragma unroll
    for (int rt = 0; rt < 4; ++rt)
#pragma unroll
        for (int j = 0; j < 4; ++j) {
            const int row = rowB + wr + rt * 16 + 4 * qd + j;
#pragma unroll
            for (int ct = 0; ct < 4; ++ct) {
                const int col = colB + wc + ct * 16 + lx;
                st_out(&C[(size_t)row * ldc + col], acc[rt][ct][j] + bias[col]);
            }
        }
}

// ---------------- RMSNorm: f32 in -> bf16 out -------------------------------
__global__ void rmsnorm_kernel(const float* __restrict__ in, __hip_bfloat16* __restrict__ outp,
                               const float* __restrict__ w,
                               int D, int in_stride, int out_stride) {
    const int row = blockIdx.x;
    const float* p = in + (size_t)row * in_stride;
    __hip_bfloat16* o = outp + (size_t)row * out_stride;
    const int tid = threadIdx.x;  // 256
    float ss = 0.f;
    for (int i = tid; i < D; i += 256) { float v = p[i]; ss += v * v; }
    __shared__ float red[256];
    red[tid] = ss;
    __syncthreads();
    for (int off = 128; off > 0; off >>= 1) {
        if (tid < off) red[tid] += red[tid + off];
        __syncthreads();
    }
    const float scale = rsqrtf(red[0] / (float)D + EPS_F);
    for (int i = tid; i < D; i += 256)
        o[i] = __float2bfloat16(p[i] * scale * w[i]);
}

// ---------------- RoPE on q (in-place on bf16 qb: (T, H*192)) ---------------
__global__ void rope_q_bf_kernel(__hip_bfloat16* __restrict__ qb,
                                 const float* __restrict__ freqs) {
    const int idx = blockIdx.x * 256 + threadIdx.x;
    const int t = idx >> 9;
    const int h = (idx >> 5) & 15;
    const int i = idx & 31;
    const float f = freqs[t * 32 + i];
    const float c = cosf(f), s = sinf(f);
    __hip_bfloat16* p = qb + (size_t)t * 3072 + h * 192 + 128 + 2 * i;
    const float xr = __bfloat162float(p[0]), xi = __bfloat162float(p[1]);
    p[0] = __float2bfloat16(xr * c - xi * s);
    p[1] = __float2bfloat16(xr * s + xi * c);
}

// ---------------- RoPE on k_pe: kvpe f32 (T,640) cols[512:576) -> kpe bf16 --
__global__ void rope_k_bf_kernel(const float* __restrict__ kvpe,
                                 const float* __restrict__ freqs,
                                 __hip_bfloat16* __restrict__ kpe) {
    const int idx = blockIdx.x * 256 + threadIdx.x;  // 65536
    const int t = idx >> 5;
    const int i = idx & 31;
    const float f = freqs[t * 32 + i];
    const float c = cosf(f), s = sinf(f);
    const float* src = kvpe + (size_t)t * 640 + 512 + 2 * i;
    const float xr = src[0], xi = src[1];
    kpe[(size_t)t * 64 + 2 * i]     = __float2bfloat16(xr * c - xi * s);
    kpe[(size_t)t * 64 + 2 * i + 1] = __float2bfloat16(xr * s + xi * c);
}

// ---------------- pack V transposed: kvb_bf (T,H*256) -> vT (H,128,T) -------
__global__ void pack_vT_kernel(const __hip_bfloat16* __restrict__ kvb,
                               __hip_bfloat16* __restrict__ vT) {
    const int t0 = blockIdx.x * 64;
    const int h = blockIdx.y;
    const int tid = threadIdx.x;
    __shared__ __hip_bfloat16 Ls[64][136];
#pragma unroll
    for (int it = 0; it < 4; ++it) {
        int c = tid + 256 * it;
        int i = c >> 4, part = c & 15;
        *(uint4*)&Ls[i][part * 8] =
            *(const uint4*)(kvb + (size_t)(t0 + i) * 4096 + h * 256 + 128 + part * 8);
    }
    __syncthreads();
#pragma unroll
    for (int it = 0; it < 32; ++it) {
        int c = tid + 256 * it;
        int d = c >> 6, i = c & 63;
        vT[((size_t)(h * 128 + d)) * 2048 + t0 + i] = Ls[i][d];
    }
}

// ---------------- MFMA flash attention (y out in bf16 now) ------------------
__global__ __launch_bounds__(256) void attn_mfma_kernel(
    const __hip_bfloat16* __restrict__ q,
    const __hip_bfloat16* __restrict__ kv,
    const __hip_bfloat16* __restrict__ kpe,
    const __hip_bfloat16* __restrict__ vT,
    __hip_bfloat16* __restrict__ y) {
    const int qt = gridDim.x - 1 - blockIdx.x;   // longest blocks first
    const int h = blockIdx.y;
    const int q0 = qt * 64;
    const int tid = threadIdx.x;
    const int w = tid >> 6, lane = tid & 63, qd = lane >> 4, lx = lane & 15;

    __shared__ __hip_bfloat16 Ks[64][200];
    __shared__ __hip_bfloat16 Vs[128][72];
    __shared__ __hip_bfloat16 Ps[4][16][72];

    short8 qf[6];
    {
        const __hip_bfloat16* qrow =
            q + (size_t)(q0 + 16 * w + lx) * 3072 + h * 192 + qd * 8;
#pragma unroll
        for (int kc = 0; kc < 6; ++kc)
            qf[kc] = *(const short8*)(qrow + kc * 32);
    }

    f32x4 O[8];
#pragma unroll
    for (int i = 0; i < 8; ++i) O[i] = (f32x4)(0.f);
    float mrow[4], lrow[4];
#pragma unroll
    for (int j = 0; j < 4; ++j) { mrow[j] = NEG_INF; lrow[j] = 0.f; }

    for (int s0 = 0; s0 <= q0 + 63; s0 += 64) {
        __syncthreads();
#pragma unroll
        for (int it = 0; it < 4; ++it) {
            int c = tid + 256 * it;
            int key = c >> 4, part = c & 15;
            *(uint4*)&Ks[key][part * 8] =
                *(const uint4*)(kv + (size_t)(s0 + key) * 4096 + h * 256 + part * 8);
        }
#pragma unroll
        for (int it = 0; it < 2; ++it) {
            int c = tid + 256 * it;
            int key = c >> 3, part = c & 7;
            *(uint4*)&Ks[key][128 + part * 8] =
                *(const uint4*)(kpe + (size_t)(s0 + key) * 64 + part * 8);
        }
#pragma unroll
        for (int it = 0; it < 4; ++it) {
            int c = tid + 256 * it;
            int dv = c >> 3, part = c & 7;
            *(uint4*)&Vs[dv][part * 8] =
                *(const uint4*)(vT + ((size_t)(h * 128 + dv)) * 2048 + s0 + part * 8);
        }
        __syncthreads();

        f32x4 S[4];
#pragma unroll
        for (int nt = 0; nt < 4; ++nt) S[nt] = (f32x4)(0.f);
#pragma unroll
        for (int kc = 0; kc < 6; ++kc) {
            short8 a = qf[kc];
#pragma unroll
            for (int nt = 0; nt < 4; ++nt) {
                short8 b = *(const short8*)&Ks[nt * 16 + lx][kc * 32 + qd * 8];
                S[nt] = __builtin_amdgcn_mfma_f32_16x16x32_bf16(a, b, S[nt], 0, 0, 0);
            }
        }

        float sv[4][4];
#pragma unroll
        for (int nt = 0; nt < 4; ++nt) {
            int col = s0 + nt * 16 + lx;
#pragma unroll
            for (int j = 0; j < 4; ++j) {
                int row = q0 + 16 * w + 4 * qd + j;
                float v = S[nt][j] * SCALE_F;
                sv[nt][j] = (col > row) ? NEG_INF : v;
            }
        }

        float mn[4], al[4], rs[4];
#pragma unroll
        for (int j = 0; j < 4; ++j) {
            float rm = fmaxf(fmaxf(sv[0][j], sv[1][j]), fmaxf(sv[2][j], sv[3][j]));
#pragma unroll
            for (int msk = 1; msk < 16; msk <<= 1)
                rm = fmaxf(rm, __shfl_xor(rm, msk));
            mn[j] = fmaxf(mrow[j], rm);
            al[j] = __expf(mrow[j] - mn[j]);
            rs[j] = 0.f;
        }
#pragma unroll
        for (int nt = 0; nt < 4; ++nt)
#pragma unroll
            for (int j = 0; j < 4; ++j) {
                float p = __expf(sv[nt][j] - mn[j]);
                rs[j] += p;
                Ps[w][4 * qd + j][nt * 16 + lx] = __float2bfloat16(p);
            }
#pragma unroll
        for (int j = 0; j < 4; ++j) {
#pragma unroll
            for (int msk = 1; msk < 16; msk <<= 1)
                rs[j] += __shfl_xor(rs[j], msk);
            lrow[j] = lrow[j] * al[j] + rs[j];
            mrow[j] = mn[j];
        }
#pragma unroll
        for (int nt = 0; nt < 8; ++nt)
#pragma unroll
            for (int j = 0; j < 4; ++j) O[nt][j] *= al[j];

        asm volatile("s_waitcnt lgkmcnt(0)" ::: "memory");

#pragma unroll
        for (int kc2 = 0; kc2 < 2; ++kc2) {
            short8 pa = *(const short8*)&Ps[w][lx][kc2 * 32 + qd * 8];
#pragma unroll
            for (int nt = 0; nt < 8; ++nt) {
                short8 vb = *(const short8*)&Vs[nt * 16 + lx][kc2 * 32 + qd * 8];
                O[nt] = __builtin_amdgcn_mfma_f32_16x16x32_bf16(pa, vb, O[nt], 0, 0, 0);
            }
        }
    }

#pragma unroll
    for (int j = 0; j < 4; ++j) {
        const float inv = 1.f / lrow[j];
        const int t = q0 + 16 * w + 4 * qd + j;
        __hip_bfloat16* yr = y + (size_t)t * 2048 + h * 128 + lx;
#pragma unroll
        for (int nt = 0; nt < 8; ++nt) yr[nt * 16] = __float2bfloat16(O[nt][j] * inv);
    }
}

extern "C" void kernel_launch(void* const* d_in, const int* in_sizes, int n_in,
                              void* d_out, int out_size, void* d_ws, size_t ws_size,
                              hipStream_t stream) {
    const float* x         = (const float*)d_in[0];
    const float* freqs     = (const float*)d_in[1];
    const float* wq_a      = (const float*)d_in[2];
    const float* bq_a      = (const float*)d_in[3];
    const float* q_norm_w  = (const float*)d_in[4];
    const float* wq_b      = (const float*)d_in[5];
    const float* bq_b      = (const float*)d_in[6];
    const float* wkv_a     = (const float*)d_in[7];
    const float* bkv_a     = (const float*)d_in[8];
    const float* kv_norm_w = (const float*)d_in[9];
    const float* wkv_b     = (const float*)d_in[10];
    const float* bkv_b     = (const float*)d_in[11];
    const float* wo        = (const float*)d_in[12];
    const float* bo        = (const float*)d_in[13];
    float* out = (float*)d_out;

    // Workspace layout, ~76.3 MB total.
    char* p = (char*)d_ws;
    float* q_lat = (float*)p;                        p += (size_t)2048 * 1536 * 4;  // later hosts yb_bf
    float* kvpe  = (float*)p;                        p += (size_t)2048 * 640 * 4;
    __hip_bfloat16* x_bf      = (__hip_bfloat16*)p;  p += (size_t)2048 * 2048 * 2;  // later hosts vT
    __hip_bfloat16* q_lat_bf  = (__hip_bfloat16*)p;  p += (size_t)2048 * 1536 * 2;
    __hip_bfloat16* qb_bf     = (__hip_bfloat16*)p;  p += (size_t)2048 * 3072 * 2;
    __hip_bfloat16* kv_lat_bf = (__hip_bfloat16*)p;  p += (size_t)2048 * 512 * 2;
    __hip_bfloat16* kvb_bf    = (__hip_bfloat16*)p;  p += (size_t)2048 * 4096 * 2;
    __hip_bfloat16* kpe_bf    = (__hip_bfloat16*)p;  p += (size_t)2048 * 64 * 2;
    __hip_bfloat16* WA        = (__hip_bfloat16*)p;  p += (size_t)3072 * 1536 * 2;  // weight arena (max 9.44 MB)
    __hip_bfloat16* WB        = (__hip_bfloat16*)p;  p += (size_t)640 * 2048 * 2;   // padded wkv_a
    float* bkv_pad = (float*)p;                      p += (size_t)640 * 4;
    __hip_bfloat16* vT    = x_bf;                    // alias: x_bf dead after GEMM 2
    __hip_bfloat16* yb_bf = (__hip_bfloat16*)q_lat;  // alias: q_lat dead after rmsnorm

    // ---- casts & pads ----
    cast_bf16_kernel<<<4096, 256, 0, stream>>>(x, x_bf, 1048576, 1048576);
    cast_bf16_kernel<<<3072, 256, 0, stream>>>(wq_a, WA, 786432, 786432);
    // GEMM 1: q_lat = x @ wq_a^T + bq_a  (f32 out)
    gemm_mfma_kernel<float><<<dim3(12, 16), 256, 0, stream>>>(x_bf, 2048, WA, 2048, bq_a, q_lat, 1536, 2048);
    cast_bf16_kernel<<<1280, 256, 0, stream>>>(wkv_a, WB, 294912, 327680);
    pad_bias_kernel<<<3, 256, 0, stream>>>(bkv_a, bkv_pad, 576, 640);
    // GEMM 2: kvpe = x @ wkv_a^T + bkv_a  (f32 out, N padded to 640)
    gemm_mfma_kernel<float><<<dim3(5, 16), 256, 0, stream>>>(x_bf, 2048, WB, 2048, bkv_pad, kvpe, 640, 2048);
    // rmsnorm q -> bf16
    rmsnorm_kernel<<<2048, 256, 0, stream>>>(q_lat, q_lat_bf, q_norm_w, 1536, 1536, 1536);
    cast_bf16_kernel<<<4608, 256, 0, stream>>>(wq_b, WA, 1179648, 1179648);
    // GEMM 3: qb_bf = q_lat_bf @ wq_b^T + bq_b
    gemm_mfma_kernel<__hip_bfloat16><<<dim3(24, 16), 256, 0, stream>>>(q_lat_bf, 1536, WA, 1536, bq_b, qb_bf, 3072, 1536);
    rope_q_bf_kernel<<<4096, 256, 0, stream>>>(qb_bf, freqs);
    rope_k_bf_kernel<<<256, 256, 0, stream>>>(kvpe, freqs, kpe_bf);
    rmsnorm_kernel<<<2048, 256, 0, stream>>>(kvpe, kv_lat_bf, kv_norm_w, 512, 640, 512);
    cast_bf16_kernel<<<2048, 256, 0, stream>>>(wkv_b, WA, 524288, 524288);
    // GEMM 4: kvb_bf = kv_lat_bf @ wkv_b^T + bkv_b
    gemm_mfma_kernel<__hip_bfloat16><<<dim3(32, 16), 256, 0, stream>>>(kv_lat_bf, 512, WA, 512, bkv_b, kvb_bf, 4096, 512);
    pack_vT_kernel<<<dim3(32, 16), 256, 0, stream>>>(kvb_bf, vT);
    attn_mfma_kernel<<<dim3(32, 16), 256, 0, stream>>>(qb_bf, kvb_bf, kpe_bf, vT, yb_bf);
    cast_bf16_kernel<<<4096, 256, 0, stream>>>(wo, WA, 1048576, 1048576);
    // GEMM 5: out = yb_bf @ wo^T + bo  (f32 out)
    gemm_mfma_kernel<float><<<dim3(16, 16), 256, 0, stream>>>(yb_bf, 2048, WA, 2048, bo, out, 2048, 2048);
}